// Round 5
// baseline (728.852 us; speedup 1.0000x reference)
//
#include <hip/hip_runtime.h>

// Problem constants (match reference)
constexpr int   T_STEPS = 64;
constexpr int   NN      = 2048;
constexpr float DT_TAU  = 0.1f;    // DT * TAU_MEM_INV
constexpr float V_TH_C  = 1.0f;
constexpr float TRC     = 0.05f;   // DT * TAU_PRE_INV == DT * TAU_POST_INV
constexpr float ETA     = 1e-3f;   // ETA_PLUS == ETA_MINUS

// 256 blocks x 512 threads (cooperative, 1 block/CU). Block b owns rows
// [8b,8b+8): one row per wave, 32 w elements + 32 tp elements per lane in
// VGPRs. Cross-block traffic: ONE u64 per block per step (8 spike bits +
// step tag). Chunk c (columns 256c..256c+255) depends only on publisher
// words 32c..32c+31 -> wave c polls its own chunk, shares via LDS flags,
// all waves process chunks in rotated order. NO __syncthreads in the loop.
constexpr int BLOCKS  = 256;
constexpr int THREADS = 512;
constexpr int RPB     = 8;         // rows per block
constexpr int CHUNKS  = 8;         // column chunks of 256

#define LD_ACQ_WG(p)   __hip_atomic_load((p), __ATOMIC_ACQUIRE, __HIP_MEMORY_SCOPE_WORKGROUP)
#define ST_REL_WG(p,v) __hip_atomic_store((p), (v), __ATOMIC_RELEASE, __HIP_MEMORY_SCOPE_WORKGROUP)

__global__ __launch_bounds__(THREADS)
void snn_pipe_kernel(const float* __restrict__ x,       // [T, N]
                     const float* __restrict__ w_in,    // [N, N] pristine
                     const float* __restrict__ tpre0,   // [N]
                     const float* __restrict__ tpost0,  // [N]
                     unsigned long long* __restrict__ zpub, // [2][BLOCKS] tag|bits
                     float*       __restrict__ out)     // [T, N] spikes
{
    const int bid  = blockIdx.x;
    const int tid  = threadIdx.x;
    const int wv   = tid >> 6;
    const int lane = tid & 63;
    const int row  = bid * RPB + wv;

    __shared__ unsigned zw_s[BLOCKS];        // low-32 of polled words (this step)
    __shared__ unsigned chunk_tag[CHUNKS];   // = t when chunk's words are in zw_s
    __shared__ float    isyn_s[RPB];
    __shared__ unsigned isyn_tag[RPB];       // = t when isyn_s[r] valid
    __shared__ unsigned zrow_s;              // this block's 8 spike bits
    __shared__ float    tpo_s8[RPB];
    __shared__ unsigned state_tag;           // = t when zrow_s/tpo_s8 valid for step t
    __shared__ float    x_s[T_STEPS * RPB];  // x for owned rows

    // init LDS flags (before any spin) + stage x for owned rows
    x_s[tid] = x[(size_t)(tid >> 3) * NN + bid * RPB + (tid & 7)];
    if (tid < CHUNKS) chunk_tag[tid] = 0xFFFFFFFFu;
    if (tid < RPB)    isyn_tag[tid]  = 0xFFFFFFFFu;
    if (tid == 0)     state_tag      = 0xFFFFFFFFu;

    // this wave's w row: chunk c holds w[row][(c*64+lane)*4 .. +3]
    const float4* wrow4 = (const float4*)(w_in + (size_t)row * NN);
    float4 wreg[CHUNKS];
    #pragma unroll
    for (int c = 0; c < CHUNKS; ++c) wreg[c] = wrow4[c * 64 + lane];
    // pre-trace for this lane's 32 columns (replicated across waves/blocks)
    float4 tpreg[CHUNKS];
    #pragma unroll
    for (int c = 0; c < CHUNKS; ++c) tpreg[c] = ((const float4*)tpre0)[c * 64 + lane];

    // owned-neuron state lives in wave 0, lanes 0..7
    float v_own = 0.0f, tpo_own = 0.0f;
    if (wv == 0 && lane < RPB) tpo_own = tpost0[bid * RPB + lane];

    __syncthreads();   // only barrier: LDS init + x_s ready

    // ---- bootstrap: step 0 (i_syn = 0), wave 0 integrates + publishes ----
    if (wv == 0) {
        float z = 0.0f;
        if (lane < RPB) {
            float v = v_own + DT_TAU * ((0.0f - v_own) + 0.0f + x_s[lane]);
            z = (v - V_TH_C > 0.0f) ? 1.0f : 0.0f;
            v_own   = v * (1.0f - z);
            tpo_own = tpo_own + TRC * (-tpo_own + z);
            out[bid * RPB + lane] = z;
            tpo_s8[lane] = tpo_own;
        }
        unsigned bits = (unsigned)(__ballot(z > 0.0f) & 0xFFull);
        if (lane == 0) {
            // tag 0 in high 32 == plain bits value
            __hip_atomic_store(&zpub[0 * BLOCKS + bid], (unsigned long long)bits,
                               __ATOMIC_RELAXED, __HIP_MEMORY_SCOPE_AGENT);
            zrow_s = bits;
            ST_REL_WG(&state_tag, 0u);    // orders zrow_s/tpo_s8 before flag
        }
    }

    // ---- steps t = 0..62: consume z_t, produce z_{t+1} ----
    for (int t = 0; t < T_STEPS - 1; ++t) {
        const int par = t & 1;

        // wait for own block's per-step state (no barrier)
        while (LD_ACQ_WG(&state_tag) != (unsigned)t) {}
        const unsigned zbits = zrow_s;
        const float tpoi = tpo_s8[wv];
        const float zi   = (float)((zbits >> wv) & 1u);
        const float a = ETA * zi;      // exact: z in {0,1}
        const float b = ETA * tpoi;

        // poll own chunk's 32 publisher words for tag t (lanes 0..31)
        const int mc = wv;
        unsigned long long w64 = 0;
        bool ok = (lane >= 32);
        for (;;) {
            if (!ok) {
                w64 = __hip_atomic_load(&zpub[par * BLOCKS + mc * 32 + lane],
                                        __ATOMIC_RELAXED, __HIP_MEMORY_SCOPE_AGENT);
                ok = ((unsigned)(w64 >> 32) == (unsigned)t);
            }
            if (__ballot(ok) == ~0ull) break;
        }
        if (lane < 32) zw_s[mc * 32 + lane] = (unsigned)w64;
        if (lane == 0) ST_REL_WG(&chunk_tag[mc], (unsigned)t);  // waits own ds writes

        // process chunks in rotated order; per-chunk partials keep the final
        // accumulation order fixed (bitwise-deterministic across waves/blocks)
        float part[CHUNKS];
        #pragma unroll
        for (int k = 0; k < CHUNKS; ++k) {
            const int c = (mc + k) & 7;
            if (k > 0) { while (LD_ACQ_WG(&chunk_tag[c]) != (unsigned)t) {} }
            const unsigned wb = zw_s[c * 32 + (lane >> 1)];   // 2-way broadcast: free
            const int sh = (lane & 1) * 4;
            float4 z4;
            z4.x = ((wb >> (sh + 0)) & 1u) ? 1.0f : 0.0f;
            z4.y = ((wb >> (sh + 1)) & 1u) ? 1.0f : 0.0f;
            z4.z = ((wb >> (sh + 2)) & 1u) ? 1.0f : 0.0f;
            z4.w = ((wb >> (sh + 3)) & 1u) ? 1.0f : 0.0f;

            tpreg[c].x = tpreg[c].x + TRC * (-tpreg[c].x + z4.x);
            tpreg[c].y = tpreg[c].y + TRC * (-tpreg[c].y + z4.y);
            tpreg[c].z = tpreg[c].z + TRC * (-tpreg[c].z + z4.z);
            tpreg[c].w = tpreg[c].w + TRC * (-tpreg[c].w + z4.w);

            float nw, pp;
            // min(nw,1) dropped: w <= 0.02 + 64*ETA*max(tp) < 0.09 << 1, provably
            nw = wreg[c].x + (a * tpreg[c].x - b * z4.x);
            nw = fmaxf(nw, 0.0f); wreg[c].x = nw; pp  = nw * z4.x;
            nw = wreg[c].y + (a * tpreg[c].y - b * z4.y);
            nw = fmaxf(nw, 0.0f); wreg[c].y = nw; pp += nw * z4.y;
            nw = wreg[c].z + (a * tpreg[c].z - b * z4.z);
            nw = fmaxf(nw, 0.0f); wreg[c].z = nw; pp += nw * z4.z;
            nw = wreg[c].w + (a * tpreg[c].w - b * z4.w);
            nw = fmaxf(nw, 0.0f); wreg[c].w = nw; pp += nw * z4.w;
            part[c] = pp;
        }
        float acc = part[0];
        #pragma unroll
        for (int c = 1; c < CHUNKS; ++c) acc += part[c];   // fixed chunk order
        #pragma unroll
        for (int m = 32; m >= 1; m >>= 1) acc += __shfl_xor(acc, m, 64);

        if (lane == 0) {
            isyn_s[wv] = acc;
            ST_REL_WG(&isyn_tag[wv], (unsigned)t);
        }

        // epilogue (wave 0): integrate step t+1 for all 8 rows, publish
        if (wv == 0) {
            float z = 0.0f;
            if (lane < RPB) {
                while (LD_ACQ_WG(&isyn_tag[lane]) != (unsigned)t) {}
                const float is = isyn_s[lane];
                float v = v_own + DT_TAU * ((0.0f - v_own) + is + x_s[(t + 1) * RPB + lane]);
                z = (v - V_TH_C > 0.0f) ? 1.0f : 0.0f;
                v_own   = v * (1.0f - z);
                tpo_own = tpo_own + TRC * (-tpo_own + z);
                out[(size_t)(t + 1) * NN + bid * RPB + lane] = z;
                tpo_s8[lane] = tpo_own;
            }
            unsigned bits = (unsigned)(__ballot(z > 0.0f) & 0xFFull);
            if (lane == 0) {
                if (t + 1 < T_STEPS - 1) {   // z_63 is never polled
                    const unsigned long long word =
                        ((unsigned long long)(unsigned)(t + 1) << 32) | bits;
                    __hip_atomic_store(&zpub[((t + 1) & 1) * BLOCKS + bid], word,
                                       __ATOMIC_RELAXED, __HIP_MEMORY_SCOPE_AGENT);
                }
                zrow_s = bits;
                ST_REL_WG(&state_tag, (unsigned)(t + 1));
            }
        }
    }
}

extern "C" void kernel_launch(void* const* d_in, const int* in_sizes, int n_in,
                              void* d_out, int out_size, void* d_ws, size_t ws_size,
                              hipStream_t stream) {
    const float* x     = (const float*)d_in[0];   // [T,N]
    const float* w_in  = (const float*)d_in[1];   // [N,N]
    const float* tpre  = (const float*)d_in[2];   // [N]
    const float* tpost = (const float*)d_in[3];   // [N]
    float*       out   = (float*)d_out;           // [T,N]

    // ws: zpub[2][256] u64 = 4 KB. 0xAA poison tag never matches a real tag
    // (0..62); parity double-buffering prevents overwriting unconsumed words.
    unsigned long long* zpub = (unsigned long long*)d_ws;

    void* args[] = {(void*)&x, (void*)&w_in, (void*)&tpre, (void*)&tpost,
                    (void*)&zpub, (void*)&out};
    hipLaunchCooperativeKernel((void*)snn_pipe_kernel,
                               dim3(BLOCKS), dim3(THREADS),
                               args, 0, stream);
}

// Round 6
// 470.270 us; speedup vs baseline: 1.5499x; 1.5499x over previous
//
#include <hip/hip_runtime.h>

// Problem constants (match reference)
constexpr int   T_STEPS = 64;
constexpr int   NN      = 2048;
constexpr float DT_TAU  = 0.1f;    // DT * TAU_MEM_INV
constexpr float V_TH_C  = 1.0f;
constexpr float TRC     = 0.05f;   // DT * TAU_PRE_INV == DT * TAU_POST_INV
constexpr float ETA     = 1e-3f;   // ETA_PLUS == ETA_MINUS

// 256 blocks x 512 threads (cooperative, 1 block/CU). Block b owns rows
// [8b,8b+8): one row per wave, w row in VGPRs (32/lane, CONSTANT-indexed
// only — dynamic indexing spills to scratch, round-5 lesson: 2 GB of spill
// traffic). Per-step cross-block traffic: each wave publishes ONE u32
// (t<<1)|spike_bit for its row; consumers poll 4 words/thread, unpack
// straight into parity-buffered LDS. One __syncthreads per step.
constexpr int BLOCKS  = 256;
constexpr int THREADS = 512;
constexpr int RPB     = 8;         // rows per block
constexpr int CHUNKS  = 8;         // column chunks of 256

__global__ __launch_bounds__(THREADS)
void snn_row_kernel(const float* __restrict__ x,       // [T, N]
                    const float* __restrict__ w_in,    // [N, N] pristine
                    const float* __restrict__ tpre0,   // [N]
                    const float* __restrict__ tpost0,  // [N]
                    unsigned*    __restrict__ zpub,    // [2][NN] (t<<1)|bit
                    float*       __restrict__ out)     // [T, N] spikes
{
    const int bid  = blockIdx.x;
    const int tid  = threadIdx.x;
    const int wv   = tid >> 6;
    const int lane = tid & 63;
    const int row  = bid * RPB + wv;

    // parity double-buffered replicated state (identical across blocks)
    __shared__ __align__(16) float z_s[2][NN];
    __shared__ __align__(16) float tp_s[2][NN];
    __shared__ float x_s[T_STEPS * RPB];      // x for owned rows

    // stage x for owned rows: x_s[t*8+r] = x[t][8*bid+r]
    x_s[tid] = x[(size_t)(tid >> 3) * NN + bid * RPB + (tid & 7)];

    // this wave's w row: chunk c holds w[row][(c*64+lane)*4 .. +3]
    const float4* wrow4 = (const float4*)(w_in + (size_t)row * NN);
    float4 wreg[CHUNKS];
    #pragma unroll
    for (int c = 0; c < CHUNKS; ++c) wreg[c] = wrow4[c * 64 + lane];

    // pre-trace for this thread's 4 columns (cols 4*tid..4*tid+3)
    float4 tp4 = ((const float4*)tpre0)[tid];

    // owned-neuron state in lane 0 of each wave
    float v_own = 0.0f, tpo_own = 0.0f;
    if (lane == 0) tpo_own = tpost0[row];

    __syncthreads();   // x_s ready

    // ---- bootstrap: step 0 (i_syn = 0): integrate own row, publish z_0 ----
    if (lane == 0) {
        float v = v_own + DT_TAU * ((0.0f - v_own) + 0.0f + x_s[wv]);
        float z = (v - V_TH_C > 0.0f) ? 1.0f : 0.0f;
        v_own   = v * (1.0f - z);
        tpo_own = tpo_own + TRC * (-tpo_own + z);
        out[row] = z;
        __hip_atomic_store(&zpub[0 * NN + row], (0u << 1) | (unsigned)z,
                           __ATOMIC_RELAXED, __HIP_MEMORY_SCOPE_AGENT);
    }

    // ---- iterations t = 0..62: consume z_t, produce+publish z_{t+1} ----
    for (int t = 0; t < T_STEPS - 1; ++t) {
        const int par = t & 1;

        // poll own 4 row-words for tag t; unpack + tp update fused in
        const unsigned* zp = zpub + (size_t)par * NN + 4 * tid;
        const unsigned tg = (unsigned)t;
        unsigned w0, w1, w2, w3;
        do {
            w0 = __hip_atomic_load(zp + 0, __ATOMIC_RELAXED, __HIP_MEMORY_SCOPE_AGENT);
            w1 = __hip_atomic_load(zp + 1, __ATOMIC_RELAXED, __HIP_MEMORY_SCOPE_AGENT);
            w2 = __hip_atomic_load(zp + 2, __ATOMIC_RELAXED, __HIP_MEMORY_SCOPE_AGENT);
            w3 = __hip_atomic_load(zp + 3, __ATOMIC_RELAXED, __HIP_MEMORY_SCOPE_AGENT);
        } while (((w0 >> 1) != tg) | ((w1 >> 1) != tg) |
                 ((w2 >> 1) != tg) | ((w3 >> 1) != tg));

        float4 z4u;
        z4u.x = (float)(w0 & 1u);
        z4u.y = (float)(w1 & 1u);
        z4u.z = (float)(w2 & 1u);
        z4u.w = (float)(w3 & 1u);
        tp4.x = tp4.x + TRC * (-tp4.x + z4u.x);
        tp4.y = tp4.y + TRC * (-tp4.y + z4u.y);
        tp4.z = tp4.z + TRC * (-tp4.z + z4u.z);
        tp4.w = tp4.w + TRC * (-tp4.w + z4u.w);
        ((float4*)z_s[par])[tid]  = z4u;
        ((float4*)tp_s[par])[tid] = tp4;
        __syncthreads();   // the ONLY barrier in the loop

        // wave-uniform scalars (exact: z in {0,1})
        const float zi   = z_s[par][row];
        const float tpoi = __shfl(tpo_own, 0, 64);
        const float a = ETA * zi;
        const float b = ETA * tpoi;

        // fused STDP w-update (registers, constant-indexed) + dot product
        float acc = 0.0f;
        const float4* z4s  = (const float4*)z_s[par];
        const float4* tp4s = (const float4*)tp_s[par];
        #pragma unroll
        for (int c = 0; c < CHUNKS; ++c) {
            float4 zj = z4s[c * 64 + lane];
            float4 tj = tp4s[c * 64 + lane];
            float nw;
            // min(nw,1) dropped: w <= 0.02 + 64*ETA*max(tp) < 0.09 << 1, provably
            nw = wreg[c].x + (a * tj.x - b * zj.x);
            nw = fmaxf(nw, 0.0f); wreg[c].x = nw; acc += nw * zj.x;
            nw = wreg[c].y + (a * tj.y - b * zj.y);
            nw = fmaxf(nw, 0.0f); wreg[c].y = nw; acc += nw * zj.y;
            nw = wreg[c].z + (a * tj.z - b * zj.z);
            nw = fmaxf(nw, 0.0f); wreg[c].z = nw; acc += nw * zj.z;
            nw = wreg[c].w + (a * tj.w - b * zj.w);
            nw = fmaxf(nw, 0.0f); wreg[c].w = nw; acc += nw * zj.w;
        }
        #pragma unroll
        for (int m = 32; m >= 1; m >>= 1) acc += __shfl_xor(acc, m, 64);

        // lane 0: integrate own neuron for t+1, write raster, publish word.
        if (lane == 0) {
            float v = v_own + DT_TAU * ((0.0f - v_own) + acc + x_s[(t + 1) * RPB + wv]);
            float z = (v - V_TH_C > 0.0f) ? 1.0f : 0.0f;
            v_own   = v * (1.0f - z);
            tpo_own = tpo_own + TRC * (-tpo_own + z);
            out[(size_t)(t + 1) * NN + row] = z;
            if (t + 1 < T_STEPS - 1) {   // z_63 is never polled
                __hip_atomic_store(&zpub[(size_t)((t + 1) & 1) * NN + row],
                                   ((unsigned)(t + 1) << 1) | (unsigned)z,
                                   __ATOMIC_RELAXED, __HIP_MEMORY_SCOPE_AGENT);
            }
        }
        // No trailing barrier: z_s/tp_s are parity-buffered. Slot par is next
        // written at t+2, gated on detecting tag t+2, which transitively
        // requires every wave here to have published t+1 — and each wave's
        // publish follows its step-t LDS reads in program order.
    }
}

extern "C" void kernel_launch(void* const* d_in, const int* in_sizes, int n_in,
                              void* d_out, int out_size, void* d_ws, size_t ws_size,
                              hipStream_t stream) {
    const float* x     = (const float*)d_in[0];   // [T,N]
    const float* w_in  = (const float*)d_in[1];   // [N,N]
    const float* tpre  = (const float*)d_in[2];   // [N]
    const float* tpost = (const float*)d_in[3];   // [N]
    float*       out   = (float*)d_out;           // [T,N]

    // ws: zpub[2][2048] u32 = 16 KB. 0xAA poison (tag 0x55555555 after >>1)
    // never matches a real tag (0..62); parity double-buffering prevents
    // overwriting unconsumed words — no initialization needed.
    unsigned* zpub = (unsigned*)d_ws;

    void* args[] = {(void*)&x, (void*)&w_in, (void*)&tpre, (void*)&tpost,
                    (void*)&zpub, (void*)&out};
    hipLaunchCooperativeKernel((void*)snn_row_kernel,
                               dim3(BLOCKS), dim3(THREADS),
                               args, 0, stream);
}

// Round 7
// 384.891 us; speedup vs baseline: 1.8937x; 1.2218x over previous
//
#include <hip/hip_runtime.h>

// Problem constants (match reference)
constexpr int   T_STEPS = 64;
constexpr int   NN      = 2048;
constexpr float DT_TAU  = 0.1f;    // DT * TAU_MEM_INV
constexpr float V_TH_C  = 1.0f;
constexpr float TRC     = 0.05f;   // DT * TAU_PRE_INV == DT * TAU_POST_INV
constexpr float ETA     = 1e-3f;   // ETA_PLUS == ETA_MINUS

// 256 blocks x 512 threads (cooperative, 1 block/CU). Block b owns rows
// [8b,8b+8): one row per wave, w row in VGPRs (32/lane, constant-indexed —
// dynamic indexing spills to scratch: round-5 lesson, 2 GB spill traffic).
// Cross-block traffic: ONE u32 per block per step ((t<<8)|8 spike bits).
// Probe budget (round-6 lesson: L3 contention scales with probes): 512
// spin-loads/block on 256 words; consumers unpack inline — no staging sync.
constexpr int BLOCKS  = 256;
constexpr int THREADS = 512;
constexpr int RPB     = 8;         // rows per block
constexpr int CHUNKS  = 8;         // column chunks of 256

__global__ __launch_bounds__(THREADS)
void snn_r7_kernel(const float* __restrict__ x,       // [T, N]
                   const float* __restrict__ w_in,    // [N, N] pristine
                   const float* __restrict__ tpre0,   // [N]
                   const float* __restrict__ tpost0,  // [N]
                   unsigned*    __restrict__ zpub,    // [2][BLOCKS] (t<<8)|bits
                   float*       __restrict__ out)     // [T, N] spikes
{
    const int bid  = blockIdx.x;
    const int tid  = threadIdx.x;
    const int wv   = tid >> 6;
    const int lane = tid & 63;
    const int row  = bid * RPB + wv;

    // Replicated state (identical across blocks). Single-buffered: all reuse
    // is gated through zpub's parity double-buffer (see end-of-loop comment).
    __shared__ __align__(16) float z_s[NN];
    __shared__ __align__(16) float tp_s[NN];
    __shared__ float zbit_s[RPB];            // this block's next spike bits
    __shared__ float x_s[T_STEPS * RPB];     // x for owned rows

    // stage x for owned rows: x_s[t*8+r] = x[t][8*bid+r]
    x_s[tid] = x[(size_t)(tid >> 3) * NN + bid * RPB + (tid & 7)];

    // this wave's w row: chunk c holds w[row][(c*64+lane)*4 .. +3]
    const float4* wrow4 = (const float4*)(w_in + (size_t)row * NN);
    float4 wreg[CHUNKS];
    #pragma unroll
    for (int c = 0; c < CHUNKS; ++c) wreg[c] = wrow4[c * 64 + lane];

    // pre-trace for this thread's 4 columns (cols 4*tid..4*tid+3)
    float4 tp4 = ((const float4*)tpre0)[tid];

    // owned-neuron state in lane 0 of each wave
    float v_own = 0.0f, tpo_own = 0.0f;
    if (lane == 0) tpo_own = tpost0[row];

    __syncthreads();   // x_s ready

    // ---- bootstrap: step 0 (i_syn = 0): integrate own row, stage bit ----
    if (lane == 0) {
        float v = v_own + DT_TAU * ((0.0f - v_own) + 0.0f + x_s[wv]);
        float z = (v - V_TH_C > 0.0f) ? 1.0f : 0.0f;
        v_own   = v * (1.0f - z);
        tpo_own = tpo_own + TRC * (-tpo_own + z);
        out[row] = z;
        zbit_s[wv] = z;
    }
    __syncthreads();
    if (wv == 0) {   // wave 0: ballot-pack 8 bits, publish tag-0 word
        float zz = (lane < RPB) ? zbit_s[lane] : 0.0f;
        unsigned bits = (unsigned)(__ballot(zz > 0.0f) & 0xFFull);
        if (lane == 0)
            __hip_atomic_store(&zpub[0 * BLOCKS + bid], (0u << 8) | bits,
                               __ATOMIC_RELAXED, __HIP_MEMORY_SCOPE_AGENT);
    }

    // ---- iterations t = 0..62: consume z_t, produce+publish z_{t+1} ----
    for (int t = 0; t < T_STEPS - 1; ++t) {
        const int par = t & 1;

        // fused poll+unpack: this thread's 4 cols (4*tid..4*tid+3) all live
        // in publisher word tid>>1 (8 rows/word). Poll it, unpack inline.
        const unsigned tg = (unsigned)t;
        unsigned w0;
        do {
            w0 = __hip_atomic_load(&zpub[par * BLOCKS + (tid >> 1)],
                                   __ATOMIC_RELAXED, __HIP_MEMORY_SCOPE_AGENT);
        } while ((w0 >> 8) != tg);

        const int sh = (tid & 1) * 4;
        float4 z4u;
        z4u.x = (float)((w0 >> (sh + 0)) & 1u);
        z4u.y = (float)((w0 >> (sh + 1)) & 1u);
        z4u.z = (float)((w0 >> (sh + 2)) & 1u);
        z4u.w = (float)((w0 >> (sh + 3)) & 1u);
        tp4.x = tp4.x + TRC * (-tp4.x + z4u.x);
        tp4.y = tp4.y + TRC * (-tp4.y + z4u.y);
        tp4.z = tp4.z + TRC * (-tp4.z + z4u.z);
        tp4.w = tp4.w + TRC * (-tp4.w + z4u.w);
        ((float4*)z_s)[tid]  = z4u;
        ((float4*)tp_s)[tid] = tp4;
        __syncthreads();   // barrier 1: z_s/tp_s ready for the dot

        // wave-uniform scalars (exact: z in {0,1})
        const float zi   = z_s[row];
        const float tpoi = __shfl(tpo_own, 0, 64);
        const float a = ETA * zi;
        const float b = ETA * tpoi;

        // fused STDP w-update (registers, constant-indexed) + dot product
        float acc = 0.0f;
        const float4* z4s  = (const float4*)z_s;
        const float4* tp4s = (const float4*)tp_s;
        #pragma unroll
        for (int c = 0; c < CHUNKS; ++c) {
            float4 zj = z4s[c * 64 + lane];
            float4 tj = tp4s[c * 64 + lane];
            float nw;
            // min(nw,1) dropped: w <= 0.02 + 64*ETA*max(tp) < 0.09 << 1, provably
            nw = wreg[c].x + (a * tj.x - b * zj.x);
            nw = fmaxf(nw, 0.0f); wreg[c].x = nw; acc += nw * zj.x;
            nw = wreg[c].y + (a * tj.y - b * zj.y);
            nw = fmaxf(nw, 0.0f); wreg[c].y = nw; acc += nw * zj.y;
            nw = wreg[c].z + (a * tj.z - b * zj.z);
            nw = fmaxf(nw, 0.0f); wreg[c].z = nw; acc += nw * zj.z;
            nw = wreg[c].w + (a * tj.w - b * zj.w);
            nw = fmaxf(nw, 0.0f); wreg[c].w = nw; acc += nw * zj.w;
        }
        #pragma unroll
        for (int m = 32; m >= 1; m >>= 1) acc += __shfl_xor(acc, m, 64);

        // integrate own neuron for t+1 right at the reduce (no isyn round-trip)
        if (lane == 0) {
            float v = v_own + DT_TAU * ((0.0f - v_own) + acc + x_s[(t + 1) * RPB + wv]);
            float z = (v - V_TH_C > 0.0f) ? 1.0f : 0.0f;
            v_own   = v * (1.0f - z);
            tpo_own = tpo_own + TRC * (-tpo_own + z);
            out[(size_t)(t + 1) * NN + row] = z;   // own row only (no block-0 straggler)
            zbit_s[wv] = z;
        }
        __syncthreads();   // barrier 2: zbit_s complete
        if (wv == 0 && t + 1 < T_STEPS - 1) {   // z_63 is never polled
            float zz = (lane < RPB) ? zbit_s[lane] : 0.0f;
            unsigned bits = (unsigned)(__ballot(zz > 0.0f) & 0xFFull);
            if (lane == 0)
                __hip_atomic_store(&zpub[((t + 1) & 1) * BLOCKS + bid],
                                   ((unsigned)(t + 1) << 8) | bits,
                                   __ATOMIC_RELAXED, __HIP_MEMORY_SCOPE_AGENT);
        }
        // Safety of single-buffered z_s/tp_s/zbit_s: a wave enters step t+1's
        // unpack-write only after passing its poll for tag t+1, which requires
        // every block's t+1 publish; our own t+1 publish happens after barrier
        // 2 of step t, i.e. after every wave here finished step t's z_s/tp_s
        // reads. zpub slot reuse (t -> t+2) is gated the same way through the
        // remote blocks' own barriers.
    }
}

extern "C" void kernel_launch(void* const* d_in, const int* in_sizes, int n_in,
                              void* d_out, int out_size, void* d_ws, size_t ws_size,
                              hipStream_t stream) {
    const float* x     = (const float*)d_in[0];   // [T,N]
    const float* w_in  = (const float*)d_in[1];   // [N,N]
    const float* tpre  = (const float*)d_in[2];   // [N]
    const float* tpost = (const float*)d_in[3];   // [N]
    float*       out   = (float*)d_out;           // [T,N]

    // ws: zpub[2][256] u32 = 2 KB. 0xAA poison gives tag 0xAAAAAA (>>8),
    // never a real tag (0..62); parity double-buffering prevents overwriting
    // unconsumed words — no initialization needed.
    unsigned* zpub = (unsigned*)d_ws;

    void* args[] = {(void*)&x, (void*)&w_in, (void*)&tpre, (void*)&tpost,
                    (void*)&zpub, (void*)&out};
    hipLaunchCooperativeKernel((void*)snn_r7_kernel,
                               dim3(BLOCKS), dim3(THREADS),
                               args, 0, stream);
}